// Round 2
// baseline (41.026 us; speedup 1.0000x reference)
//
#include <hip/hip_runtime.h>

#define BB 4
#define TT 128
#define CC 256
#define HH 8
#define EE 64
#define DD 32
#define ROWS (BB*TT)          // 512
#define SENT (-3.402823466e38f)

// ws layout (floats)
#define OFF_QKP   0            // [512][8][64]
#define OFF_VNODE 262144       // [512][256]

__device__ __forceinline__ float dot4(float4 a, float4 b) {
    return a.x*b.x + a.y*b.y + a.z*b.z + a.w*b.w;
}

// ---------------- K1: q -> qkp, v_node (raw weights, no pre-transpose) ----
// grid 256: rb = blk>>2 (8 rows each), cb = blk&3 (64 cols / 2 heads). 512 thr.
__global__ void k1_proj(const float* __restrict__ x, const float* __restrict__ Wq,
                        const float* __restrict__ Wv, const float* __restrict__ Wk,
                        const float* __restrict__ bq, const float* __restrict__ bv,
                        float* __restrict__ vnode, float* __restrict__ qkp) {
    __shared__ float xT[256*8];     // [k][r]
    __shared__ float redq[8*512];   // [kq][r*64+cc]
    __shared__ float redv[8*512];
    __shared__ float qls[8*64];     // [r][cc]
    int tid = threadIdx.x;
    int rb = blockIdx.x >> 2, cb = blockIdx.x & 3;
    int r0 = rb*8, c0 = cb*64, h0 = cb*2;

    {   // load x rows transposed
        int fid = tid*4;
        int r = fid >> 8, k = fid & 255;
        float4 xv = *(const float4*)&x[(r0 + r)*256 + k];
        xT[(k+0)*8 + r] = xv.x; xT[(k+1)*8 + r] = xv.y;
        xT[(k+2)*8 + r] = xv.z; xT[(k+3)*8 + r] = xv.w;
    }
    __syncthreads();

    int cc = tid & 63, kq = tid >> 6;
    int c = c0 + cc;
    float aq[8] = {0,0,0,0,0,0,0,0};
    float av[8] = {0,0,0,0,0,0,0,0};
    const float* wq_row = Wq + (size_t)c*256 + kq*32;
    const float* wv_row = Wv + (size_t)c*320 + kq*32;
    #pragma unroll
    for (int i = 0; i < 8; ++i) {
        float4 wq4 = *(const float4*)&wq_row[i*4];
        float4 wv4 = *(const float4*)&wv_row[i*4];
        int kbase = kq*32 + i*4;
        #pragma unroll
        for (int t = 0; t < 4; ++t) {
            float wq = (t==0)?wq4.x:(t==1)?wq4.y:(t==2)?wq4.z:wq4.w;
            float wv = (t==0)?wv4.x:(t==1)?wv4.y:(t==2)?wv4.z:wv4.w;
            int k = kbase + t;
            float4 xa = *(float4*)&xT[k*8];
            float4 xb = *(float4*)&xT[k*8 + 4];
            aq[0] += xa.x*wq; aq[1] += xa.y*wq; aq[2] += xa.z*wq; aq[3] += xa.w*wq;
            aq[4] += xb.x*wq; aq[5] += xb.y*wq; aq[6] += xb.z*wq; aq[7] += xb.w*wq;
            av[0] += xa.x*wv; av[1] += xa.y*wv; av[2] += xa.z*wv; av[3] += xa.w*wv;
            av[4] += xb.x*wv; av[5] += xb.y*wv; av[6] += xb.z*wv; av[7] += xb.w*wv;
        }
    }
    #pragma unroll
    for (int r = 0; r < 8; ++r) {
        redq[kq*512 + r*64 + cc] = aq[r];
        redv[kq*512 + r*64 + cc] = av[r];
    }
    __syncthreads();
    {   // reduce partials
        int r = tid >> 6, c2 = tid & 63;
        float sq = bq[c0 + c2], sv = bv[c0 + c2];
        #pragma unroll
        for (int k2 = 0; k2 < 8; ++k2) {
            sq += redq[k2*512 + r*64 + c2];
            sv += redv[k2*512 + r*64 + c2];
        }
        qls[r*64 + c2] = sq;
        vnode[(size_t)(r0 + r)*256 + c0 + c2] = sv;
    }
    __syncthreads();
    {   // qkp: per row r, local head hl, 2 e's; raw Wk edge columns, scaled
        int r = tid >> 6, rem = tid & 63;
        int hl = rem >> 5, e0 = (rem & 31)*2;
        int ch = h0 + hl;
        const float* wk_base = Wk + (size_t)(ch*32)*320 + 256 + e0;
        float ax = 0.f, ay = 0.f;
        #pragma unroll 8
        for (int d = 0; d < 32; ++d) {
            float qd = qls[r*64 + hl*32 + d];
            float2 w2 = *(const float2*)&wk_base[(size_t)d*320];
            ax += qd*w2.x; ay += qd*w2.y;
        }
        ax *= 0.17677669529663687f;   // 1/sqrt(32)
        ay *= 0.17677669529663687f;
        float2 acc = {ax, ay};
        *(float2*)&qkp[(size_t)(r0 + r)*512 + ch*64 + e0] = acc;
    }
}

// ---------------- K2: fused attention over edge + output projection --------
// grid 512 (one per (b,i)), 512 thr.
__global__ void k2_attn(const float* __restrict__ edge, const int* __restrict__ msk,
                        const float* __restrict__ qkp, const float* __restrict__ vnode,
                        const float* __restrict__ Wv, const float* __restrict__ Wp,
                        const float* __restrict__ bp, float* __restrict__ out) {
    __shared__ float eds[128*68];   // edge row-major, stride 68 (16B-aligned rows)
    __shared__ float attL[8*132];   // logits -> weights, stride 132
    __shared__ float qkpL[8*64];
    __shared__ float aggP[2*8*64];  // [jh][h][e]
    __shared__ float aggF[8*64];
    __shared__ float mval[128];
    __shared__ float yL[256];

    int tid = threadIdx.x;
    int wv = tid >> 6, lane = tid & 63;
    int row = blockIdx.x;

    const float* eg = edge + (size_t)row * (TT*EE);
    #pragma unroll
    for (int it = 0; it < 4; ++it) {
        int fid = (tid + 512*it)*4;
        int j = fid >> 6, e = fid & 63;
        float4 v = *(const float4*)(eg + fid);
        *(float4*)&eds[j*68 + e] = v;
    }
    qkpL[tid] = qkp[(size_t)row*512 + tid];
    if (tid < 128) mval[tid] = (msk[row*128 + tid] != 0) ? 1.0f : 0.0f;
    __syncthreads();

    {   // logits: wave = (head-pair, j-half)
        int hp = wv >> 1, jh = wv & 1, h0 = hp*2;
        int j = jh*64 + lane;
        float a0 = 0.f, a1 = 0.f;
        #pragma unroll
        for (int ec = 0; ec < 16; ++ec) {
            float4 ev = *(float4*)&eds[j*68 + ec*4];
            float4 qa = *(float4*)&qkpL[h0*64 + ec*4];
            float4 qb = *(float4*)&qkpL[(h0+1)*64 + ec*4];
            a0 += dot4(ev, qa);
            a1 += dot4(ev, qb);
        }
        float valid = mval[j];
        attL[h0*132 + j]     = (valid > 0.5f) ? a0 : SENT;
        attL[(h0+1)*132 + j] = (valid > 0.5f) ? a1 : SENT;
    }
    __syncthreads();

    {   // softmax: wave wv handles head wv
        int h = wv;
        float v0 = attL[h*132 + lane];
        float v1 = attL[h*132 + 64 + lane];
        float m = fmaxf(v0, v1);
        #pragma unroll
        for (int off = 32; off >= 1; off >>= 1) m = fmaxf(m, __shfl_xor(m, off));
        float e0 = __expf(v0 - m), e1 = __expf(v1 - m);
        float s = e0 + e1;
        #pragma unroll
        for (int off = 32; off >= 1; off >>= 1) s += __shfl_xor(s, off);
        float inv = 1.0f / s;
        attL[h*132 + lane]      = e0 * inv;
        attL[h*132 + 64 + lane] = e1 * inv;
    }
    __syncthreads();

    {   // edge_agg: wave = (head-pair, j-half); lane = (jj, ec)
        int hp = wv >> 1, jh = wv & 1, h0 = hp*2;
        int jj = lane & 3, ec = lane >> 2;
        float4 a0 = {0,0,0,0}, a1 = {0,0,0,0};
        #pragma unroll
        for (int js = 0; js < 16; ++js) {
            int j = jh*64 + js*4 + jj;
            float4 ev = *(float4*)&eds[j*68 + ec*4];
            float w0 = attL[h0*132 + j];
            float w1 = attL[(h0+1)*132 + j];
            a0.x += w0*ev.x; a0.y += w0*ev.y; a0.z += w0*ev.z; a0.w += w0*ev.w;
            a1.x += w1*ev.x; a1.y += w1*ev.y; a1.z += w1*ev.z; a1.w += w1*ev.w;
        }
        #pragma unroll
        for (int off = 1; off <= 2; off <<= 1) {
            a0.x += __shfl_xor(a0.x, off); a0.y += __shfl_xor(a0.y, off);
            a0.z += __shfl_xor(a0.z, off); a0.w += __shfl_xor(a0.w, off);
            a1.x += __shfl_xor(a1.x, off); a1.y += __shfl_xor(a1.y, off);
            a1.z += __shfl_xor(a1.z, off); a1.w += __shfl_xor(a1.w, off);
        }
        if (jj == 0) {
            *(float4*)&aggP[jh*512 + h0*64 + ec*4]     = a0;
            *(float4*)&aggP[jh*512 + (h0+1)*64 + ec*4] = a1;
        }
    }
    __syncthreads();
    aggF[tid] = aggP[tid] + aggP[512 + tid];
    __syncthreads();

    if (tid < 256) {   // y = v_node + agg @ WvE^T (raw Wv edge cols)
        int h = tid >> 5;
        const float* wve = Wv + (size_t)tid*320 + 256;
        float acc = vnode[(size_t)row*256 + tid];
        #pragma unroll
        for (int ec = 0; ec < 16; ++ec) {
            float4 ag = *(float4*)&aggF[h*64 + ec*4];
            float4 w4 = *(const float4*)&wve[ec*4];
            acc += dot4(ag, w4);
        }
        yL[tid] = acc;
    }
    __syncthreads();

    {   // out projection: out[o] = bp[o] + y . Wp[o][:]
        int o = tid >> 1, chh = tid & 1;
        const float* wpr = Wp + (size_t)o*256 + chh*128;
        float acc = 0.f;
        #pragma unroll 8
        for (int i = 0; i < 32; ++i) {
            float4 w4 = *(const float4*)&wpr[i*4];
            float4 y4 = *(float4*)&yL[chh*128 + i*4];
            acc += dot4(w4, y4);
        }
        acc += __shfl_xor(acc, 1);
        if (chh == 0) out[(size_t)row*256 + o] = acc + bp[o];
    }
}

extern "C" void kernel_launch(void* const* d_in, const int* in_sizes, int n_in,
                              void* d_out, int out_size, void* d_ws, size_t ws_size,
                              hipStream_t stream) {
    (void)in_sizes; (void)n_in; (void)out_size; (void)ws_size;
    const float* x    = (const float*)d_in[0];
    // d_in[1] aux_x: unused by reference
    const int*   msk  = (const int*)d_in[2];
    const float* edge = (const float*)d_in[3];
    const float* Wq   = (const float*)d_in[4];
    const float* bq   = (const float*)d_in[5];
    const float* Wk   = (const float*)d_in[6];
    // d_in[7] bk: constant over j -> cancels in softmax, never needed
    const float* Wv   = (const float*)d_in[8];
    const float* bv   = (const float*)d_in[9];
    const float* Wp   = (const float*)d_in[10];
    const float* bp   = (const float*)d_in[11];
    float* out = (float*)d_out;
    float* ws  = (float*)d_ws;

    float* qkp   = ws + OFF_QKP;
    float* vnode = ws + OFF_VNODE;

    k1_proj<<<256, 512, 0, stream>>>(x, Wq, Wv, Wk, bq, bv, vnode, qkp);
    k2_attn<<<512, 512, 0, stream>>>(edge, msk, qkp, vnode, Wv, Wp, bp, out);
}

// Round 3
// 35.259 us; speedup vs baseline: 1.1636x; 1.1636x over previous
//
#include <hip/hip_runtime.h>

#define BB 4
#define TT 128
#define CC 256
#define HH 8
#define EE 64
#define DD 32
#define ROWS (BB*TT)          // 512
#define SENT (-3.402823466e38f)

// ws layout (floats)
#define OFF_WQT   0            // [256][256]  WqT[k][c] = Wq[c][k]
#define OFF_WVNT  65536        // [256][256]  WvnT[k][c] = Wv[c][k] (node cols)
#define OFF_WPT   131072       // [256][256]  WpT[k][c] = Wp[c][k]
#define OFF_WKES  196608       // [256][64]   Wk[c][256+e] * (1/sqrt(D)) [c][e]
#define OFF_WVET  212992       // [64][256]   WvEt[e][c] = Wv[c][256+e]
#define OFF_QKP   229376       // [512][8][64]
#define OFF_VNODE 491520       // [512][256]
#define OFF_YBUF  622592       // [512][256]

__device__ __forceinline__ float dot4(float4 a, float4 b) {
    return a.x*b.x + a.y*b.y + a.z*b.z + a.w*b.w;
}

// ---------------- K0: weight transposes / extractions ----------------
__global__ void k0_setup(const float* __restrict__ Wq, const float* __restrict__ Wv,
                         const float* __restrict__ Wp, const float* __restrict__ Wk,
                         float* __restrict__ WqT, float* __restrict__ WvnT,
                         float* __restrict__ WpT, float* __restrict__ WkEs,
                         float* __restrict__ WvEt) {
    __shared__ float tile[32][33];
    int blk = blockIdx.x, tid = threadIdx.x;
    if (blk < 192) {
        int m = blk >> 6, t = blk & 63;
        int tr = t >> 3, tc = t & 7;          // tile row (c-dim), tile col (k-dim)
        const float* src; int ss; float* dst;
        if (m == 0)      { src = Wq; ss = 256; dst = WqT; }
        else if (m == 1) { src = Wv; ss = 320; dst = WvnT; }
        else             { src = Wp; ss = 256; dst = WpT; }
        #pragma unroll
        for (int i = 0; i < 4; ++i) {
            int rr = i*8 + (tid >> 5), kk = tid & 31;
            tile[rr][kk] = src[(size_t)(tr*32 + rr)*ss + tc*32 + kk];
        }
        __syncthreads();
        #pragma unroll
        for (int i = 0; i < 4; ++i) {
            int kk = i*8 + (tid >> 5), rr = tid & 31;
            dst[(size_t)(tc*32 + kk)*256 + tr*32 + rr] = tile[rr][kk];
        }
    } else if (blk < 208) {   // WvEt: [256c][64e] -> [64e][256c], 16 tiles (8c x 2e)
        int t = blk - 192;
        int tr = t >> 1, tc = t & 1;          // tr: c-tile, tc: e-tile
        #pragma unroll
        for (int i = 0; i < 4; ++i) {
            int rr = i*8 + (tid >> 5), kk = tid & 31;   // rr: c-local, kk: e-local
            tile[rr][kk] = Wv[(size_t)(tr*32 + rr)*320 + 256 + tc*32 + kk];
        }
        __syncthreads();
        #pragma unroll
        for (int i = 0; i < 4; ++i) {
            int kk = i*8 + (tid >> 5), rr = tid & 31;
            WvEt[(size_t)(tc*32 + kk)*256 + tr*32 + rr] = tile[rr][kk];
        }
    } else {                  // WkEs extract + scale, [256][64], 16 blocks
        int bb = blk - 208;
        int gid = bb*1024 + tid*4;
        int c = gid >> 6, e = gid & 63;
        const float s = 0.17677669529663687f;   // 1/sqrt(32)
        float4 v = *(const float4*)&Wk[(size_t)c*320 + 256 + e];
        v.x *= s; v.y *= s; v.z *= s; v.w *= s;
        *(float4*)&WkEs[c*64 + e] = v;
    }
}

// ---------------- K1: q (-> qkp), v_node ----------------
// grid 256: rb = blk>>2 (8 rows each), cb = blk&3 (64 cols / 2 heads). 512 thr.
__global__ void k1_proj(const float* __restrict__ x, const float* __restrict__ WqT,
                        const float* __restrict__ WvnT, const float* __restrict__ WkEs,
                        const float* __restrict__ bq, const float* __restrict__ bv,
                        float* __restrict__ vnode, float* __restrict__ qkp) {
    __shared__ float xT[256*8];     // [k][r]
    __shared__ float redq[8*512];   // [kq][r*64+cc]
    __shared__ float redv[8*512];
    __shared__ float qls[8*64];     // [r][cc]
    int tid = threadIdx.x;
    int rb = blockIdx.x >> 2, cb = blockIdx.x & 3;
    int r0 = rb*8, c0 = cb*64, h0 = cb*2;

    {   // load x rows transposed
        int fid = tid*4;
        int r = fid >> 8, k = fid & 255;
        float4 xv = *(const float4*)&x[(size_t)(r0 + r)*256 + k];
        xT[(k+0)*8 + r] = xv.x; xT[(k+1)*8 + r] = xv.y;
        xT[(k+2)*8 + r] = xv.z; xT[(k+3)*8 + r] = xv.w;
    }
    __syncthreads();

    int cc = tid & 63, kq = tid >> 6;
    int c = c0 + cc;
    float aq[8] = {0,0,0,0,0,0,0,0};
    float av[8] = {0,0,0,0,0,0,0,0};
    #pragma unroll 8
    for (int k = kq*32; k < kq*32 + 32; ++k) {
        float wq = WqT[k*256 + c];
        float wv = WvnT[k*256 + c];
        float4 xa = *(float4*)&xT[k*8];
        float4 xb = *(float4*)&xT[k*8 + 4];
        aq[0] += xa.x*wq; aq[1] += xa.y*wq; aq[2] += xa.z*wq; aq[3] += xa.w*wq;
        aq[4] += xb.x*wq; aq[5] += xb.y*wq; aq[6] += xb.z*wq; aq[7] += xb.w*wq;
        av[0] += xa.x*wv; av[1] += xa.y*wv; av[2] += xa.z*wv; av[3] += xa.w*wv;
        av[4] += xb.x*wv; av[5] += xb.y*wv; av[6] += xb.z*wv; av[7] += xb.w*wv;
    }
    #pragma unroll
    for (int r = 0; r < 8; ++r) {
        redq[kq*512 + r*64 + cc] = aq[r];
        redv[kq*512 + r*64 + cc] = av[r];
    }
    __syncthreads();
    {   // reduce partials
        int r = tid >> 6, c2 = tid & 63;
        float sq = bq[c0 + c2], sv = bv[c0 + c2];
        #pragma unroll
        for (int k2 = 0; k2 < 8; ++k2) {
            sq += redq[k2*512 + r*64 + c2];
            sv += redv[k2*512 + r*64 + c2];
        }
        qls[r*64 + c2] = sq;
        vnode[(size_t)(r0 + r)*256 + c0 + c2] = sv;
    }
    __syncthreads();
    {   // qkp: per row r, local head hl, 2 e's
        int r = tid >> 6, rem = tid & 63;
        int hl = rem >> 5, e0 = (rem & 31)*2;
        float2 acc = {0.f, 0.f};
        #pragma unroll
        for (int d = 0; d < 32; ++d) {
            float qd = qls[r*64 + hl*32 + d];
            float2 w2 = *(const float2*)&WkEs[((h0+hl)*32 + d)*64 + e0];
            acc.x += qd*w2.x; acc.y += qd*w2.y;
        }
        *(float2*)&qkp[(size_t)(r0 + r)*512 + (h0+hl)*64 + e0] = acc;
    }
}

// ---------------- K2: fused attention over edge ----------------
// grid 512 (one per (b,i)), 512 thr.
__global__ void k2_attn(const float* __restrict__ edge, const int* __restrict__ msk,
                        const float* __restrict__ qkp, const float* __restrict__ vnode,
                        const float* __restrict__ WvEt, float* __restrict__ ybuf) {
    __shared__ float eds[128*68];   // edge row-major, stride 68 (16B-aligned rows)
    __shared__ float attL[8*132];   // logits -> weights, stride 132
    __shared__ float qkpL[8*64];
    __shared__ float aggP[2*8*64];  // [jh][h][e]
    __shared__ float aggF[8*64];
    __shared__ float mval[128];
    __shared__ float redY[2*256];

    int tid = threadIdx.x;
    int wv = tid >> 6, lane = tid & 63;
    int row = blockIdx.x;

    const float* eg = edge + (size_t)row * (TT*EE);
    #pragma unroll
    for (int it = 0; it < 4; ++it) {
        int fid = (tid + 512*it)*4;
        int j = fid >> 6, e = fid & 63;
        float4 v = *(const float4*)(eg + fid);
        *(float4*)&eds[j*68 + e] = v;
    }
    qkpL[tid] = qkp[(size_t)row*512 + tid];
    if (tid < 128) mval[tid] = (msk[row*128 + tid] != 0) ? 1.0f : 0.0f;
    __syncthreads();

    {   // logits: wave = (head-pair, j-half)
        int hp = wv >> 1, jh = wv & 1, h0 = hp*2;
        int j = jh*64 + lane;
        float a0 = 0.f, a1 = 0.f;
        #pragma unroll
        for (int ec = 0; ec < 16; ++ec) {
            float4 ev = *(float4*)&eds[j*68 + ec*4];
            float4 qa = *(float4*)&qkpL[h0*64 + ec*4];
            float4 qb = *(float4*)&qkpL[(h0+1)*64 + ec*4];
            a0 += dot4(ev, qa);
            a1 += dot4(ev, qb);
        }
        float valid = mval[j];
        attL[h0*132 + j]     = (valid > 0.5f) ? a0 : SENT;
        attL[(h0+1)*132 + j] = (valid > 0.5f) ? a1 : SENT;
    }
    __syncthreads();

    {   // softmax: wave wv handles head wv
        int h = wv;
        float v0 = attL[h*132 + lane];
        float v1 = attL[h*132 + 64 + lane];
        float m = fmaxf(v0, v1);
        #pragma unroll
        for (int off = 32; off >= 1; off >>= 1) m = fmaxf(m, __shfl_xor(m, off));
        float e0 = __expf(v0 - m), e1 = __expf(v1 - m);
        float s = e0 + e1;
        #pragma unroll
        for (int off = 32; off >= 1; off >>= 1) s += __shfl_xor(s, off);
        float inv = 1.0f / s;
        attL[h*132 + lane]      = e0 * inv;
        attL[h*132 + 64 + lane] = e1 * inv;
    }
    __syncthreads();

    {   // edge_agg: wave = (head-pair, j-half); lane = (jj, ec)
        int hp = wv >> 1, jh = wv & 1, h0 = hp*2;
        int jj = lane & 3, ec = lane >> 2;
        float4 a0 = {0,0,0,0}, a1 = {0,0,0,0};
        #pragma unroll
        for (int js = 0; js < 16; ++js) {
            int j = jh*64 + js*4 + jj;
            float4 ev = *(float4*)&eds[j*68 + ec*4];
            float w0 = attL[h0*132 + j];
            float w1 = attL[(h0+1)*132 + j];
            a0.x += w0*ev.x; a0.y += w0*ev.y; a0.z += w0*ev.z; a0.w += w0*ev.w;
            a1.x += w1*ev.x; a1.y += w1*ev.y; a1.z += w1*ev.z; a1.w += w1*ev.w;
        }
        #pragma unroll
        for (int off = 1; off <= 2; off <<= 1) {
            a0.x += __shfl_xor(a0.x, off); a0.y += __shfl_xor(a0.y, off);
            a0.z += __shfl_xor(a0.z, off); a0.w += __shfl_xor(a0.w, off);
            a1.x += __shfl_xor(a1.x, off); a1.y += __shfl_xor(a1.y, off);
            a1.z += __shfl_xor(a1.z, off); a1.w += __shfl_xor(a1.w, off);
        }
        if (jj == 0) {
            *(float4*)&aggP[jh*512 + h0*64 + ec*4]     = a0;
            *(float4*)&aggP[jh*512 + (h0+1)*64 + ec*4] = a1;
        }
    }
    __syncthreads();
    aggF[tid] = aggP[tid] + aggP[512 + tid];
    __syncthreads();

    {   // y partials: y[c] = vnode[c] + sum_e aggF[h(c)][e] * WvEt[e][c]
        int c = tid & 255, eh = tid >> 8;
        int h = c >> 5;
        const float* wv_col = WvEt + (size_t)(eh*32)*256 + c;
        float acc = 0.f;
        #pragma unroll
        for (int it = 0; it < 32; ++it) {
            acc += aggF[h*64 + eh*32 + it] * wv_col[(size_t)it*256];
        }
        redY[eh*256 + c] = acc;
    }
    __syncthreads();
    if (tid < 256) {
        ybuf[(size_t)row*256 + tid] =
            vnode[(size_t)row*256 + tid] + redY[tid] + redY[256 + tid];
    }
}

// ---------------- K3: output projection (row-batched, coalesced WpT) -------
__global__ void k3_out(const float* __restrict__ ybuf, const float* __restrict__ WpT,
                       const float* __restrict__ bp, float* __restrict__ out) {
    __shared__ float yT[256*8];
    __shared__ float red[8*512];
    int tid = threadIdx.x;
    int rb = blockIdx.x >> 2, cb = blockIdx.x & 3;
    int r0 = rb*8, c0 = cb*64;
    {
        int fid = tid*4;
        int r = fid >> 8, k = fid & 255;
        float4 yv = *(const float4*)&ybuf[(size_t)(r0 + r)*256 + k];
        yT[(k+0)*8 + r] = yv.x; yT[(k+1)*8 + r] = yv.y;
        yT[(k+2)*8 + r] = yv.z; yT[(k+3)*8 + r] = yv.w;
    }
    __syncthreads();
    int cc = tid & 63, kq = tid >> 6;
    int c = c0 + cc;
    float acc[8] = {0,0,0,0,0,0,0,0};
    #pragma unroll 8
    for (int k = kq*32; k < kq*32 + 32; ++k) {
        float wp = WpT[k*256 + c];
        float4 xa = *(float4*)&yT[k*8];
        float4 xb = *(float4*)&yT[k*8 + 4];
        acc[0] += xa.x*wp; acc[1] += xa.y*wp; acc[2] += xa.z*wp; acc[3] += xa.w*wp;
        acc[4] += xb.x*wp; acc[5] += xb.y*wp; acc[6] += xb.z*wp; acc[7] += xb.w*wp;
    }
    #pragma unroll
    for (int r = 0; r < 8; ++r) red[kq*512 + r*64 + cc] = acc[r];
    __syncthreads();
    {
        int r = tid >> 6, c2 = tid & 63;
        float s = bp[c0 + c2];
        #pragma unroll
        for (int k2 = 0; k2 < 8; ++k2) s += red[k2*512 + r*64 + c2];
        out[(size_t)(r0 + r)*256 + c0 + c2] = s;
    }
}

extern "C" void kernel_launch(void* const* d_in, const int* in_sizes, int n_in,
                              void* d_out, int out_size, void* d_ws, size_t ws_size,
                              hipStream_t stream) {
    (void)in_sizes; (void)n_in; (void)out_size; (void)ws_size;
    const float* x    = (const float*)d_in[0];
    // d_in[1] aux_x: unused by reference
    const int*   msk  = (const int*)d_in[2];
    const float* edge = (const float*)d_in[3];
    const float* Wq   = (const float*)d_in[4];
    const float* bq   = (const float*)d_in[5];
    const float* Wk   = (const float*)d_in[6];
    // d_in[7] bk: constant over j -> cancels in softmax, never needed
    const float* Wv   = (const float*)d_in[8];
    const float* bv   = (const float*)d_in[9];
    const float* Wp   = (const float*)d_in[10];
    const float* bp   = (const float*)d_in[11];
    float* out = (float*)d_out;
    float* ws  = (float*)d_ws;

    float* WqT   = ws + OFF_WQT;
    float* WvnT  = ws + OFF_WVNT;
    float* WpT   = ws + OFF_WPT;
    float* WkEs  = ws + OFF_WKES;
    float* WvEt  = ws + OFF_WVET;
    float* qkp   = ws + OFF_QKP;
    float* vnode = ws + OFF_VNODE;
    float* ybuf  = ws + OFF_YBUF;

    k0_setup<<<224, 256, 0, stream>>>(Wq, Wv, Wp, Wk, WqT, WvnT, WpT, WkEs, WvEt);
    k1_proj<<<256, 512, 0, stream>>>(x, WqT, WvnT, WkEs, bq, bv, vnode, qkp);
    k2_attn<<<512, 512, 0, stream>>>(edge, msk, qkp, vnode, WvEt, ybuf);
    k3_out<<<256, 512, 0, stream>>>(ybuf, WpT, bp, out);
}